// Round 4
// baseline (721.264 us; speedup 1.0000x reference)
//
#include <hip/hip_runtime.h>
#include <math.h>

#define NPTS 500000
#define M_ASSIGN 400000
#define WPR 15625  // 500000/32 words per bitmap row

// workspace layout (float units)
constexpr int    OFF_ACC      = 0;        // [0]=nll_sum [1]=valid_cnt [2]=l1_sum [3]=cos_sum [4]=mask_sum
constexpr int    OFF_SUM      = 64;       // 64 BN sums (of raw h, no b1)
constexpr int    OFF_SQ       = 128;      // 64 BN sumsq
constexpr int    OFF_BITMAP   = 320;      // 2,000,000 uint32
constexpr int    OFF_SEGPRED  = 2000320;  // 500,000 int
constexpr int    OFF_PROBS    = 2500448;  // 10,000,000 float
constexpr size_t OFF_H        = 12500448; // 16,000,000 bf16 (8,000,000 float slots)

__device__ inline unsigned bf16rne(float x) {
  unsigned u = __float_as_uint(x);
  return (u + 0x7fffu + ((u >> 16) & 1u)) >> 16;
}
__device__ inline unsigned pack2bf16(float a, float b) {
  return bf16rne(a) | (bf16rne(b) << 16);
}

// ---------------------------------------------------------------------------
// Pass 1 (fused): h = feat@w1 (bf16 store) + BN stats + logits = feat@seg_w+b
//                 + softmax->probs + argmax->segp + NLL partials.
// feat staged transposed in LDS (coalesced global, conflict-free ds_read);
// weights via block-uniform scalar loads.
// ---------------------------------------------------------------------------
__global__ __launch_bounds__(256) void pass1_kernel(
    const float* __restrict__ feat, const float* __restrict__ w1,
    const float* __restrict__ seg_w, const float* __restrict__ seg_b,
    const int* __restrict__ segment, float* __restrict__ ws)
{
  __shared__ float fs[16][258];   // [k within chunk][point] ; stride 258 -> <=2-way banks
  __shared__ float lsum[64], lsq[64];
  __shared__ float rn[4], rv[4];

  float* acc   = ws + OFF_ACC;
  float* gsum  = ws + OFF_SUM;
  float* gsq   = ws + OFF_SQ;
  int*   segp  = (int*)(ws + OFF_SEGPRED);
  float* probs = ws + OFF_PROBS;
  unsigned short* hbuf = (unsigned short*)(ws + OFF_H);

  const int tid = threadIdx.x;
  const int n0 = blockIdx.x * 256;
  const int n = n0 + tid;
  const bool valid = (n < NPTS);

  if (tid < 64) { lsum[tid] = 0.f; lsq[tid] = 0.f; }

  float hacc[64];
  #pragma unroll
  for (int c = 0; c < 64; ++c) hacc[c] = 0.f;
  float sacc[20];
  #pragma unroll
  for (int j = 0; j < 20; ++j) sacc[j] = seg_b[j];

  for (int c = 0; c < 4; ++c) {
    // stage chunk c: k in [16c, 16c+16) for all 256 points, transposed
    #pragma unroll
    for (int j = 0; j < 4; ++j) {
      const int flat = j * 256 + tid;  // float4-unit index in 256x16 tile
      const int p = flat >> 2;         // point within block
      const int u = flat & 3;          // which float4 of the 16-float row
      const int gp = n0 + p;
      float4 v = make_float4(0.f, 0.f, 0.f, 0.f);
      if (gp < NPTS) v = *(const float4*)(feat + (size_t)gp * 64 + c * 16 + u * 4);
      fs[u * 4 + 0][p] = v.x;
      fs[u * 4 + 1][p] = v.y;
      fs[u * 4 + 2][p] = v.z;
      fs[u * 4 + 3][p] = v.w;
    }
    __syncthreads();

    #pragma unroll 2
    for (int k = 0; k < 16; ++k) {
      const float fk = fs[k][tid];
      const int kk = c * 16 + k;
      const float* wr = w1 + kk * 64;      // uniform -> s_load
      const float* sr = seg_w + kk * 20;   // uniform -> s_load
      #pragma unroll
      for (int ch = 0; ch < 64; ++ch) hacc[ch] = fmaf(fk, wr[ch], hacc[ch]);
      #pragma unroll
      for (int ch = 0; ch < 20; ++ch) sacc[ch] = fmaf(fk, sr[ch], sacc[ch]);
    }
    __syncthreads();
  }

  float nll = 0.f, vld = 0.f;
  if (valid) {
    // store raw h as bf16
    uint4* hv4 = (uint4*)(hbuf + (size_t)n * 64);
    #pragma unroll
    for (int i = 0; i < 8; ++i) {
      uint4 v;
      v.x = pack2bf16(hacc[8 * i + 0], hacc[8 * i + 1]);
      v.y = pack2bf16(hacc[8 * i + 2], hacc[8 * i + 3]);
      v.z = pack2bf16(hacc[8 * i + 4], hacc[8 * i + 5]);
      v.w = pack2bf16(hacc[8 * i + 6], hacc[8 * i + 7]);
      hv4[i] = v;
    }
    // BN stats via staggered LDS atomics
    const int lane = tid & 63;
    #pragma unroll
    for (int cg = 0; cg < 16; ++cg) {
      const int c0 = 4 * ((cg + lane) & 15);
      atomicAdd(&lsum[c0 + 0], hacc[c0 + 0]); atomicAdd(&lsq[c0 + 0], hacc[c0 + 0] * hacc[c0 + 0]);
      atomicAdd(&lsum[c0 + 1], hacc[c0 + 1]); atomicAdd(&lsq[c0 + 1], hacc[c0 + 1] * hacc[c0 + 1]);
      atomicAdd(&lsum[c0 + 2], hacc[c0 + 2]); atomicAdd(&lsq[c0 + 2], hacc[c0 + 2] * hacc[c0 + 2]);
      atomicAdd(&lsum[c0 + 3], hacc[c0 + 3]); atomicAdd(&lsq[c0 + 3], hacc[c0 + 3] * hacc[c0 + 3]);
    }
    // softmax / argmax / nll
    const int seg = segment[n];
    const bool svalid = (seg != -1);
    const int sidx = seg < 0 ? 0 : (seg > 19 ? 19 : seg);
    float m = sacc[0]; int bi = 0;
    #pragma unroll
    for (int j = 1; j < 20; ++j) { if (sacc[j] > m) { m = sacc[j]; bi = j; } }
    float lsv = sacc[0];
    #pragma unroll
    for (int j = 1; j < 20; ++j) lsv = (j == sidx) ? sacc[j] : lsv;
    float se = 0.f;
    #pragma unroll
    for (int j = 0; j < 20; ++j) { sacc[j] = __expf(sacc[j] - m); se += sacc[j]; }
    const float inv = 1.f / se;
    float4* pr = (float4*)(probs + (size_t)n * 20);
    pr[0] = make_float4(sacc[0]*inv,  sacc[1]*inv,  sacc[2]*inv,  sacc[3]*inv);
    pr[1] = make_float4(sacc[4]*inv,  sacc[5]*inv,  sacc[6]*inv,  sacc[7]*inv);
    pr[2] = make_float4(sacc[8]*inv,  sacc[9]*inv,  sacc[10]*inv, sacc[11]*inv);
    pr[3] = make_float4(sacc[12]*inv, sacc[13]*inv, sacc[14]*inv, sacc[15]*inv);
    pr[4] = make_float4(sacc[16]*inv, sacc[17]*inv, sacc[18]*inv, sacc[19]*inv);
    segp[n] = bi;
    nll = svalid ? (m + __logf(se) - lsv) : 0.f;
    vld = svalid ? 1.f : 0.f;
  }

  #pragma unroll
  for (int o = 32; o > 0; o >>= 1) {
    nll += __shfl_down(nll, o);
    vld += __shfl_down(vld, o);
  }
  if ((tid & 63) == 0) { rn[tid >> 6] = nll; rv[tid >> 6] = vld; }
  __syncthreads();
  if (tid == 0) {
    atomicAdd(&acc[0], rn[0] + rn[1] + rn[2] + rn[3]);
    atomicAdd(&acc[1], rv[0] + rv[1] + rv[2] + rv[3]);
  }
  if (tid < 64) { atomicAdd(&gsum[tid], lsum[tid]); atomicAdd(&gsq[tid], lsq[tid]); }
}

// ---------------------------------------------------------------------------
// Pass 2: BN (recomputed per block) + ReLU + w2 head + L1/cosine loss partials
// ---------------------------------------------------------------------------
__global__ __launch_bounds__(256) void bias_loss_kernel(
    const float* __restrict__ coord, const float* __restrict__ cent,
    const float* __restrict__ gamma, const float* __restrict__ beta,
    const float* __restrict__ w2, const float* __restrict__ b2,
    const int* __restrict__ instance, float* __restrict__ ws)
{
  __shared__ float scs[64], shs[64];
  __shared__ float r0[4], r1[4], r2[4];
  float* acc = ws + OFF_ACC;
  const unsigned short* hbuf = (const unsigned short*)(ws + OFF_H);

  const int tid = threadIdx.x;
  if (tid < 64) {
    const float mu  = ws[OFF_SUM + tid] * (1.f / NPTS);
    const float var = ws[OFF_SQ  + tid] * (1.f / NPTS) - mu * mu;
    const float sc = gamma[tid] * rsqrtf(var + 0.001f);
    scs[tid] = sc;
    shs[tid] = beta[tid] - mu * sc;   // b1 cancels through BN
  }
  __syncthreads();

  const int n = blockIdx.x * 256 + tid;
  float l1v = 0.f, cosv = 0.f, mk = 0.f;
  if (n < NPTS) {
    float bx = b2[0], by = b2[1], bz = b2[2];
    const uint4* hv = (const uint4*)(hbuf + (size_t)n * 64);
    #pragma unroll
    for (int i = 0; i < 8; ++i) {
      const uint4 v = hv[i];
      const unsigned uu[4] = {v.x, v.y, v.z, v.w};
      #pragma unroll
      for (int j = 0; j < 4; ++j) {
        const int c = i * 8 + j * 2;
        const float lo = __uint_as_float(uu[j] << 16);
        const float hi = __uint_as_float(uu[j] & 0xffff0000u);
        const float h0 = fmaxf(fmaf(lo, scs[c],     shs[c]),     0.f);
        const float h1 = fmaxf(fmaf(hi, scs[c + 1], shs[c + 1]), 0.f);
        bx = fmaf(h0, w2[c * 3 + 0], bx);
        by = fmaf(h0, w2[c * 3 + 1], by);
        bz = fmaf(h0, w2[c * 3 + 2], bz);
        bx = fmaf(h1, w2[c * 3 + 3], bx);
        by = fmaf(h1, w2[c * 3 + 4], by);
        bz = fmaf(h1, w2[c * 3 + 5], bz);
      }
    }
    const float cx = coord[(size_t)n*3+0], cy = coord[(size_t)n*3+1], cz = coord[(size_t)n*3+2];
    const float ex = cent[(size_t)n*3+0],  ey = cent[(size_t)n*3+1],  ez = cent[(size_t)n*3+2];
    const float gx = ex - cx, gy = ey - cy, gz = ez - cz;
    const float dx = bx - gx, dy = by - gy, dz = bz - gz;
    const float l1 = fabsf(dx) + fabsf(dy) + fabsf(dz);
    const float npn = sqrtf(bx*bx + by*by + bz*bz) + 1e-8f;
    const float ngn = sqrtf(gx*gx + gy*gy + gz*gz) + 1e-8f;
    const float cv = -(bx*gx + by*gy + bz*gz) / (npn * ngn);
    mk = (instance[n] != -1) ? 1.f : 0.f;
    l1v = l1 * mk;
    cosv = cv * mk;
  }
  #pragma unroll
  for (int o = 32; o > 0; o >>= 1) {
    l1v  += __shfl_down(l1v, o);
    cosv += __shfl_down(cosv, o);
    mk   += __shfl_down(mk, o);
  }
  if ((tid & 63) == 0) { r0[tid>>6] = l1v; r1[tid>>6] = cosv; r2[tid>>6] = mk; }
  __syncthreads();
  if (tid == 0) {
    atomicAdd(&acc[2], r0[0]+r0[1]+r0[2]+r0[3]);
    atomicAdd(&acc[3], r1[0]+r1[1]+r1[2]+r1[3]);
    atomicAdd(&acc[4], r2[0]+r2[1]+r2[2]+r2[3]);
  }
}

__global__ __launch_bounds__(256) void assign_kernel(
    const int* __restrict__ prop_ids, const int* __restrict__ point_ids, float* __restrict__ ws)
{
  unsigned* bitmap = (unsigned*)(ws + OFF_BITMAP);
  const int i = blockIdx.x * 256 + threadIdx.x;
  if (i < M_ASSIGN) {
    const int p = prop_ids[i];
    const int n = point_ids[i];
    atomicOr(&bitmap[p * WPR + (n >> 5)], 1u << (n & 31));
  }
}

// ---------------------------------------------------------------------------
// Per-proposal score (inline first-index search + final loss on p==0)
// ---------------------------------------------------------------------------
__global__ __launch_bounds__(256) void score_kernel(
    const int* __restrict__ prop_ids, const int* __restrict__ point_ids,
    const float* __restrict__ ws, float* __restrict__ out)
{
  const unsigned* bitmap = (const unsigned*)(ws + OFF_BITMAP);
  const float* probs = ws + OFF_PROBS;
  const int* segp = (const int*)(ws + OFF_SEGPRED);
  __shared__ float rs[4];
  __shared__ int rc[4];
  const int p = blockIdx.x;
  const int tid = threadIdx.x;

  int lo = 0, hi = M_ASSIGN;
  while (lo < hi) { const int mid = (lo + hi) >> 1; if (prop_ids[mid] < p) lo = mid + 1; else hi = mid; }
  if (lo > M_ASSIGN - 1) lo = M_ASSIGN - 1;
  const int cp = segp[point_ids[lo]];

  float s = 0.f; int cnt = 0;
  for (int w = tid; w < WPR; w += 256) {
    unsigned bits = bitmap[p * WPR + w];
    cnt += __popc(bits);
    while (bits) {
      const int b = __ffs(bits) - 1;
      bits &= bits - 1;
      const int n = (w << 5) + b;
      s += probs[(size_t)n * 20 + cp];
    }
  }
  #pragma unroll
  for (int o = 32; o > 0; o >>= 1) { s += __shfl_down(s, o); cnt += __shfl_down(cnt, o); }
  if ((tid & 63) == 0) { rs[tid>>6] = s; rc[tid>>6] = cnt; }
  __syncthreads();
  if (tid == 0) {
    const float st = rs[0]+rs[1]+rs[2]+rs[3];
    const int ct = rc[0]+rc[1]+rc[2]+rc[3];
    const bool mk = ct > 100;
    out[1 + p]   = mk ? st / (float)(ct > 1 ? ct : 1) : 0.f;
    out[129 + p] = mk ? 1.f : 0.f;
    if (p == 0) {
      const float segl = ws[0] / fmaxf(ws[1], 1.f);
      const float d = ws[4] + 1e-8f;
      out[0] = segl + ws[2] / d + ws[3] / d;
    }
  }
}

extern "C" void kernel_launch(void* const* d_in, const int* in_sizes, int n_in,
                              void* d_out, int out_size, void* d_ws, size_t ws_size,
                              hipStream_t stream) {
  const float* feat    = (const float*)d_in[0];
  const float* coord   = (const float*)d_in[1];
  const float* cent    = (const float*)d_in[2];
  const float* w1      = (const float*)d_in[3];
  // d_in[4] = b1 : cancels through BN, unused
  const float* gamma   = (const float*)d_in[5];
  const float* beta    = (const float*)d_in[6];
  const float* w2      = (const float*)d_in[7];
  const float* b2      = (const float*)d_in[8];
  const float* seg_w   = (const float*)d_in[9];
  const float* seg_b   = (const float*)d_in[10];
  const int* segment   = (const int*)d_in[11];
  const int* instance  = (const int*)d_in[12];
  const int* prop_ids  = (const int*)d_in[13];
  const int* point_ids = (const int*)d_in[14];
  float* out = (float*)d_out;
  float* ws  = (float*)d_ws;

  // zero accumulators + BN sums + bitmap
  hipMemsetAsync(d_ws, 0, (size_t)(OFF_BITMAP + 2000000) * sizeof(float), stream);

  pass1_kernel<<<1954, 256, 0, stream>>>(feat, w1, seg_w, seg_b, segment, ws);
  bias_loss_kernel<<<1954, 256, 0, stream>>>(coord, cent, gamma, beta, w2, b2, instance, ws);
  assign_kernel<<<1563, 256, 0, stream>>>(prop_ids, point_ids, ws);
  score_kernel<<<128, 256, 0, stream>>>(prop_ids, point_ids, ws, out);
}

// Round 5
// 678.858 us; speedup vs baseline: 1.0625x; 1.0625x over previous
//
#include <hip/hip_runtime.h>
#include <math.h>

#define NPTS 500000
#define M_ASSIGN 400000
#define WPR 15625   // 500000/32 words per bitmap row
#define NTILES 7813 // ceil(500000/64)

// workspace layout (float units)
constexpr int    OFF_ACC      = 0;        // [0]=nll_sum [1]=valid_cnt [2]=l1_sum [3]=cos_sum [4]=mask_sum
constexpr int    OFF_SUM      = 64;       // 64 BN sums (of raw h, no b1)
constexpr int    OFF_SQ       = 128;      // 64 BN sumsq
constexpr int    OFF_BITMAP   = 320;      // 2,000,000 uint32
constexpr int    OFF_SEGPRED  = 2000320;  // 500,000 int
constexpr int    OFF_PROBS    = 2500448;  // 10,000,000 float
constexpr size_t OFF_H        = 12500448; // 16,000,000 bf16

__device__ inline unsigned bf16rne(float x) {
  unsigned u = __float_as_uint(x);
  return (u + 0x7fffu + ((u >> 16) & 1u)) >> 16;
}
__device__ inline unsigned pack2bf16(float a, float b) {
  return bf16rne(a) | (bf16rne(b) << 16);
}

// ---------------------------------------------------------------------------
// Pass 1: h = feat@w1 (bf16 store) + BN stats + logits/softmax/argmax/NLL.
// Block = 256 thr = 4 waves; wave g owns h-channels [16g,16g+16) and logit
// channels [5g,5g+5) for the tile's 64 points (lane = point).
// feat staged in LDS; weights via guaranteed-uniform scalar loads.
// ---------------------------------------------------------------------------
__global__ __launch_bounds__(256, 6) void pass1_kernel(
    const float* __restrict__ feat, const float* __restrict__ w1g,
    const float* __restrict__ seg_w, const float* __restrict__ seg_b,
    const int* __restrict__ segment, float* __restrict__ ws)
{
  __shared__ float fs[64][66];   // [point][k], pad 66 -> 2-way banks (free)
  __shared__ float lg[64][21];   // [point][logit]

  float* acc   = ws + OFF_ACC;
  float* gsum  = ws + OFF_SUM;
  float* gsq   = ws + OFF_SQ;
  int*   segp  = (int*)(ws + OFF_SEGPRED);
  float* probs = ws + OFF_PROBS;
  unsigned short* hbuf = (unsigned short*)(ws + OFF_H);

  const int tid  = threadIdx.x;
  const int lane = tid & 63;
  const int gu   = __builtin_amdgcn_readfirstlane(tid >> 6);  // wave id, provably uniform

  float sb[5];
  #pragma unroll
  for (int c = 0; c < 5; ++c) sb[c] = seg_b[gu * 5 + c];

  float bnsum[16], bnsq[16];
  #pragma unroll
  for (int c = 0; c < 16; ++c) { bnsum[c] = 0.f; bnsq[c] = 0.f; }
  float nll_acc = 0.f, vld_acc = 0.f;

  for (int tile = blockIdx.x; tile < NTILES; tile += gridDim.x) {
    const int n0 = tile * 64;

    // stage 64 points x 64 k (16 KB), coalesced
    #pragma unroll
    for (int j = 0; j < 4; ++j) {
      const int idx = j * 256 + tid;
      const int p = idx >> 4;
      const int u = idx & 15;
      const int gp = n0 + p;
      float4 v = make_float4(0.f, 0.f, 0.f, 0.f);
      if (gp < NPTS) v = ((const float4*)(feat + (size_t)gp * 64))[u];
      fs[p][u * 4 + 0] = v.x;
      fs[p][u * 4 + 1] = v.y;
      fs[p][u * 4 + 2] = v.z;
      fs[p][u * 4 + 3] = v.w;
    }
    __syncthreads();

    float hacc[16];
    #pragma unroll
    for (int c = 0; c < 16; ++c) hacc[c] = 0.f;
    float sacc[5];
    #pragma unroll
    for (int c = 0; c < 5; ++c) sacc[c] = sb[c];

    for (int k = 0; k < 64; k += 2) {
      const float2 f2 = *(const float2*)&fs[lane][k];
      const float* w0 = w1g + k * 64 + gu * 16;        // uniform -> s_load
      const float* w1r = w1g + (k + 1) * 64 + gu * 16;
      const float* s0 = seg_w + k * 20 + gu * 5;
      const float* s1 = seg_w + (k + 1) * 20 + gu * 5;
      #pragma unroll
      for (int c = 0; c < 16; ++c)
        hacc[c] = fmaf(f2.y, w1r[c], fmaf(f2.x, w0[c], hacc[c]));
      #pragma unroll
      for (int c = 0; c < 5; ++c)
        sacc[c] = fmaf(f2.y, s1[c], fmaf(f2.x, s0[c], sacc[c]));
    }

    const int n = n0 + lane;
    if (n < NPTS) {
      // store this wave's 16 channels as bf16 (32 B)
      unsigned short* hp = hbuf + (size_t)n * 64 + gu * 16;
      uint4 a;
      a.x = pack2bf16(hacc[0], hacc[1]);
      a.y = pack2bf16(hacc[2], hacc[3]);
      a.z = pack2bf16(hacc[4], hacc[5]);
      a.w = pack2bf16(hacc[6], hacc[7]);
      *(uint4*)hp = a;
      uint4 b;
      b.x = pack2bf16(hacc[8],  hacc[9]);
      b.y = pack2bf16(hacc[10], hacc[11]);
      b.z = pack2bf16(hacc[12], hacc[13]);
      b.w = pack2bf16(hacc[14], hacc[15]);
      *(uint4*)(hp + 8) = b;
    }
    // BN partials in registers (zero-padded tail contributes 0)
    #pragma unroll
    for (int c = 0; c < 16; ++c) { bnsum[c] += hacc[c]; bnsq[c] += hacc[c] * hacc[c]; }
    // logits to LDS
    #pragma unroll
    for (int c = 0; c < 5; ++c) lg[lane][gu * 5 + c] = sacc[c];
    __syncthreads();

    if (gu == 0 && n < NPTS) {
      float l[20];
      #pragma unroll
      for (int j = 0; j < 20; ++j) l[j] = lg[lane][j];
      const int seg = segment[n];
      const bool svalid = (seg != -1);
      const int sidx = seg < 0 ? 0 : (seg > 19 ? 19 : seg);
      float m = l[0]; int bi = 0;
      #pragma unroll
      for (int j = 1; j < 20; ++j) { if (l[j] > m) { m = l[j]; bi = j; } }
      float lsv = l[0];
      #pragma unroll
      for (int j = 1; j < 20; ++j) lsv = (j == sidx) ? l[j] : lsv;
      float se = 0.f;
      #pragma unroll
      for (int j = 0; j < 20; ++j) { l[j] = __expf(l[j] - m); se += l[j]; }
      const float inv = 1.f / se;
      float4* pr = (float4*)(probs + (size_t)n * 20);
      pr[0] = make_float4(l[0]*inv,  l[1]*inv,  l[2]*inv,  l[3]*inv);
      pr[1] = make_float4(l[4]*inv,  l[5]*inv,  l[6]*inv,  l[7]*inv);
      pr[2] = make_float4(l[8]*inv,  l[9]*inv,  l[10]*inv, l[11]*inv);
      pr[3] = make_float4(l[12]*inv, l[13]*inv, l[14]*inv, l[15]*inv);
      pr[4] = make_float4(l[16]*inv, l[17]*inv, l[18]*inv, l[19]*inv);
      segp[n] = bi;
      nll_acc += svalid ? (m + __logf(se) - lsv) : 0.f;
      vld_acc += svalid ? 1.f : 0.f;
    }
    // next iteration's staging sync doubles as the lg-read barrier
  }

  // BN: reduce partials across the wave's 64 lanes (lane = point slot)
  #pragma unroll
  for (int c = 0; c < 16; ++c) {
    float s = bnsum[c], q = bnsq[c];
    #pragma unroll
    for (int o = 32; o > 0; o >>= 1) { s += __shfl_down(s, o); q += __shfl_down(q, o); }
    if (lane == 0) {
      atomicAdd(&gsum[gu * 16 + c], s);
      atomicAdd(&gsq[gu * 16 + c], q);
    }
  }
  if (gu == 0) {
    float s = nll_acc, v = vld_acc;
    #pragma unroll
    for (int o = 32; o > 0; o >>= 1) { s += __shfl_down(s, o); v += __shfl_down(v, o); }
    if (lane == 0) { atomicAdd(&acc[0], s); atomicAdd(&acc[1], v); }
  }
}

// ---------------------------------------------------------------------------
// Pass 2: BN (recomputed per block) + ReLU + w2 head + L1/cosine partials
// ---------------------------------------------------------------------------
__global__ __launch_bounds__(256, 6) void bias_loss_kernel(
    const float* __restrict__ coord, const float* __restrict__ cent,
    const float* __restrict__ gamma, const float* __restrict__ beta,
    const float* __restrict__ w2, const float* __restrict__ b2,
    const int* __restrict__ instance, float* __restrict__ ws)
{
  __shared__ float scs[64], shs[64];
  __shared__ float r0[4], r1[4], r2[4];
  float* acc = ws + OFF_ACC;
  const unsigned short* hbuf = (const unsigned short*)(ws + OFF_H);

  const int tid = threadIdx.x;
  if (tid < 64) {
    const float mu  = ws[OFF_SUM + tid] * (1.f / NPTS);
    const float var = ws[OFF_SQ  + tid] * (1.f / NPTS) - mu * mu;
    const float sc = gamma[tid] * rsqrtf(var + 0.001f);
    scs[tid] = sc;
    shs[tid] = beta[tid] - mu * sc;   // b1 cancels through BN
  }
  __syncthreads();

  const int n = blockIdx.x * 256 + tid;
  float l1v = 0.f, cosv = 0.f, mk = 0.f;
  if (n < NPTS) {
    // issue all 8 h-loads up-front (avoid cache-thrash re-fetch)
    uint4 hv[8];
    const uint4* hp = (const uint4*)(hbuf + (size_t)n * 64);
    #pragma unroll
    for (int i = 0; i < 8; ++i) hv[i] = hp[i];

    float bx = b2[0], by = b2[1], bz = b2[2];
    #pragma unroll
    for (int i = 0; i < 8; ++i) {
      const unsigned uu[4] = {hv[i].x, hv[i].y, hv[i].z, hv[i].w};
      #pragma unroll
      for (int j = 0; j < 4; ++j) {
        const int c = i * 8 + j * 2;
        const float lo = __uint_as_float(uu[j] << 16);
        const float hi = __uint_as_float(uu[j] & 0xffff0000u);
        const float h0 = fmaxf(fmaf(lo, scs[c],     shs[c]),     0.f);
        const float h1 = fmaxf(fmaf(hi, scs[c + 1], shs[c + 1]), 0.f);
        bx = fmaf(h0, w2[c * 3 + 0], bx);
        by = fmaf(h0, w2[c * 3 + 1], by);
        bz = fmaf(h0, w2[c * 3 + 2], bz);
        bx = fmaf(h1, w2[c * 3 + 3], bx);
        by = fmaf(h1, w2[c * 3 + 4], by);
        bz = fmaf(h1, w2[c * 3 + 5], bz);
      }
    }
    const float cx = coord[(size_t)n*3+0], cy = coord[(size_t)n*3+1], cz = coord[(size_t)n*3+2];
    const float ex = cent[(size_t)n*3+0],  ey = cent[(size_t)n*3+1],  ez = cent[(size_t)n*3+2];
    const float gx = ex - cx, gy = ey - cy, gz = ez - cz;
    const float dx = bx - gx, dy = by - gy, dz = bz - gz;
    const float l1 = fabsf(dx) + fabsf(dy) + fabsf(dz);
    const float npn = sqrtf(bx*bx + by*by + bz*bz) + 1e-8f;
    const float ngn = sqrtf(gx*gx + gy*gy + gz*gz) + 1e-8f;
    const float cv = -(bx*gx + by*gy + bz*gz) / (npn * ngn);
    mk = (instance[n] != -1) ? 1.f : 0.f;
    l1v = l1 * mk;
    cosv = cv * mk;
  }
  #pragma unroll
  for (int o = 32; o > 0; o >>= 1) {
    l1v  += __shfl_down(l1v, o);
    cosv += __shfl_down(cosv, o);
    mk   += __shfl_down(mk, o);
  }
  if ((tid & 63) == 0) { r0[tid>>6] = l1v; r1[tid>>6] = cosv; r2[tid>>6] = mk; }
  __syncthreads();
  if (tid == 0) {
    atomicAdd(&acc[2], r0[0]+r0[1]+r0[2]+r0[3]);
    atomicAdd(&acc[3], r1[0]+r1[1]+r1[2]+r1[3]);
    atomicAdd(&acc[4], r2[0]+r2[1]+r2[2]+r2[3]);
  }
}

__global__ __launch_bounds__(256) void assign_kernel(
    const int* __restrict__ prop_ids, const int* __restrict__ point_ids, float* __restrict__ ws)
{
  unsigned* bitmap = (unsigned*)(ws + OFF_BITMAP);
  const int i = blockIdx.x * 256 + threadIdx.x;
  if (i < M_ASSIGN) {
    const int p = prop_ids[i];
    const int n = point_ids[i];
    atomicOr(&bitmap[p * WPR + (n >> 5)], 1u << (n & 31));
  }
}

// ---------------------------------------------------------------------------
// Per-proposal score (inline first-index search + final loss on p==0)
// ---------------------------------------------------------------------------
__global__ __launch_bounds__(256) void score_kernel(
    const int* __restrict__ prop_ids, const int* __restrict__ point_ids,
    const float* __restrict__ ws, float* __restrict__ out)
{
  const unsigned* bitmap = (const unsigned*)(ws + OFF_BITMAP);
  const float* probs = ws + OFF_PROBS;
  const int* segp = (const int*)(ws + OFF_SEGPRED);
  __shared__ float rs[4];
  __shared__ int rc[4];
  const int p = blockIdx.x;
  const int tid = threadIdx.x;

  int lo = 0, hi = M_ASSIGN;
  while (lo < hi) { const int mid = (lo + hi) >> 1; if (prop_ids[mid] < p) lo = mid + 1; else hi = mid; }
  if (lo > M_ASSIGN - 1) lo = M_ASSIGN - 1;
  const int cp = segp[point_ids[lo]];

  float s = 0.f; int cnt = 0;
  for (int w = tid; w < WPR; w += 256) {
    unsigned bits = bitmap[p * WPR + w];
    cnt += __popc(bits);
    while (bits) {
      const int b = __ffs(bits) - 1;
      bits &= bits - 1;
      const int n = (w << 5) + b;
      s += probs[(size_t)n * 20 + cp];
    }
  }
  #pragma unroll
  for (int o = 32; o > 0; o >>= 1) { s += __shfl_down(s, o); cnt += __shfl_down(cnt, o); }
  if ((tid & 63) == 0) { rs[tid>>6] = s; rc[tid>>6] = cnt; }
  __syncthreads();
  if (tid == 0) {
    const float st = rs[0]+rs[1]+rs[2]+rs[3];
    const int ct = rc[0]+rc[1]+rc[2]+rc[3];
    const bool mk = ct > 100;
    out[1 + p]   = mk ? st / (float)(ct > 1 ? ct : 1) : 0.f;
    out[129 + p] = mk ? 1.f : 0.f;
    if (p == 0) {
      const float segl = ws[0] / fmaxf(ws[1], 1.f);
      const float d = ws[4] + 1e-8f;
      out[0] = segl + ws[2] / d + ws[3] / d;
    }
  }
}

extern "C" void kernel_launch(void* const* d_in, const int* in_sizes, int n_in,
                              void* d_out, int out_size, void* d_ws, size_t ws_size,
                              hipStream_t stream) {
  const float* feat    = (const float*)d_in[0];
  const float* coord   = (const float*)d_in[1];
  const float* cent    = (const float*)d_in[2];
  const float* w1      = (const float*)d_in[3];
  // d_in[4] = b1 : cancels through BN, unused
  const float* gamma   = (const float*)d_in[5];
  const float* beta    = (const float*)d_in[6];
  const float* w2      = (const float*)d_in[7];
  const float* b2      = (const float*)d_in[8];
  const float* seg_w   = (const float*)d_in[9];
  const float* seg_b   = (const float*)d_in[10];
  const int* segment   = (const int*)d_in[11];
  const int* instance  = (const int*)d_in[12];
  const int* prop_ids  = (const int*)d_in[13];
  const int* point_ids = (const int*)d_in[14];
  float* out = (float*)d_out;
  float* ws  = (float*)d_ws;

  // zero accumulators + BN sums + bitmap
  hipMemsetAsync(d_ws, 0, (size_t)(OFF_BITMAP + 2000000) * sizeof(float), stream);

  pass1_kernel<<<1024, 256, 0, stream>>>(feat, w1, seg_w, seg_b, segment, ws);
  bias_loss_kernel<<<1954, 256, 0, stream>>>(coord, cent, gamma, beta, w2, b2, instance, ws);
  assign_kernel<<<1563, 256, 0, stream>>>(prop_ids, point_ids, ws);
  score_kernel<<<128, 256, 0, stream>>>(prop_ids, point_ids, ws, out);
}

// Round 6
// 484.165 us; speedup vs baseline: 1.4897x; 1.4021x over previous
//
#include <hip/hip_runtime.h>
#include <math.h>

#define NPTS 500000
#define M_ASSIGN 400000
#define WPR 15625   // 500000/32 words per bitmap row
#define NTILES 7813 // ceil(500000/64)

// workspace layout (float units)
constexpr int    OFF_ACC      = 0;        // [0]=nll_sum [1]=valid_cnt [2]=l1_sum [3]=cos_sum [4]=mask_sum
constexpr int    OFF_SUM      = 64;       // 64 BN sums (of raw h, no b1)
constexpr int    OFF_SQ       = 128;      // 64 BN sumsq
constexpr int    OFF_BITMAP   = 320;      // 2,000,000 uint32
constexpr int    OFF_SEGPRED  = 2000320;  // 500,000 int
constexpr int    OFF_PROBS    = 2500448;  // 10,000,000 float
constexpr size_t OFF_H        = 12500448; // 16,000,000 bf16

__device__ inline unsigned bf16rne(float x) {
  unsigned u = __float_as_uint(x);
  return (u + 0x7fffu + ((u >> 16) & 1u)) >> 16;
}

// ---------------------------------------------------------------------------
// K1: h = feat@w1 (bf16 store) + BN per-channel stats.
// 1 wave per block; lane = output channel; w1 column held in 64 VGPRs/lane.
// feat tile (64 pts x 64 k) staged in LDS; compute reads are wave-uniform
// broadcasts (conflict-free). 4 points in flight for ILP.
// ---------------------------------------------------------------------------
__global__ __launch_bounds__(64) void h_kernel(
    const float* __restrict__ feat, const float* __restrict__ w1,
    float* __restrict__ ws)
{
  __shared__ float fs[64][68];   // rows 272B (16B-aligned); uniform reads broadcast
  unsigned short* hbuf = (unsigned short*)(ws + OFF_H);
  const int lane = threadIdx.x;

  float wreg[64];                 // w1[k][lane], static-indexed only
  #pragma unroll
  for (int k = 0; k < 64; ++k) wreg[k] = w1[k * 64 + lane];

  float bnsum = 0.f, bnsq = 0.f;

  for (int tile = blockIdx.x; tile < NTILES; tile += gridDim.x) {
    const int n0 = tile * 64;
    #pragma unroll
    for (int j = 0; j < 16; ++j) {
      const int flat = j * 64 + lane;   // float4-unit index in 64x16 tile
      const int p = flat >> 4, u = flat & 15;
      const int gp = n0 + p;
      float4 v = make_float4(0.f, 0.f, 0.f, 0.f);
      if (gp < NPTS) v = ((const float4*)(feat + (size_t)gp * 64))[u];
      *(float4*)&fs[p][u * 4] = v;
    }
    __syncthreads();

    #pragma unroll 1
    for (int p0 = 0; p0 < 64; p0 += 4) {
      float a0 = 0.f, a1 = 0.f, a2 = 0.f, a3 = 0.f;
      #pragma unroll
      for (int k = 0; k < 64; k += 4) {
        const float4 f0 = *(const float4*)&fs[p0 + 0][k];
        const float4 f1 = *(const float4*)&fs[p0 + 1][k];
        const float4 f2 = *(const float4*)&fs[p0 + 2][k];
        const float4 f3 = *(const float4*)&fs[p0 + 3][k];
        a0 = fmaf(f0.x, wreg[k], a0); a0 = fmaf(f0.y, wreg[k + 1], a0);
        a0 = fmaf(f0.z, wreg[k + 2], a0); a0 = fmaf(f0.w, wreg[k + 3], a0);
        a1 = fmaf(f1.x, wreg[k], a1); a1 = fmaf(f1.y, wreg[k + 1], a1);
        a1 = fmaf(f1.z, wreg[k + 2], a1); a1 = fmaf(f1.w, wreg[k + 3], a1);
        a2 = fmaf(f2.x, wreg[k], a2); a2 = fmaf(f2.y, wreg[k + 1], a2);
        a2 = fmaf(f2.z, wreg[k + 2], a2); a2 = fmaf(f2.w, wreg[k + 3], a2);
        a3 = fmaf(f3.x, wreg[k], a3); a3 = fmaf(f3.y, wreg[k + 1], a3);
        a3 = fmaf(f3.z, wreg[k + 2], a3); a3 = fmaf(f3.w, wreg[k + 3], a3);
      }
      bnsum += (a0 + a1) + (a2 + a3);   // padded pts staged as 0 -> contribute 0
      bnsq  += (a0 * a0 + a1 * a1) + (a2 * a2 + a3 * a3);
      const int n = n0 + p0;
      if (n + 0 < NPTS) hbuf[(size_t)(n + 0) * 64 + lane] = (unsigned short)bf16rne(a0);
      if (n + 1 < NPTS) hbuf[(size_t)(n + 1) * 64 + lane] = (unsigned short)bf16rne(a1);
      if (n + 2 < NPTS) hbuf[(size_t)(n + 2) * 64 + lane] = (unsigned short)bf16rne(a2);
      if (n + 3 < NPTS) hbuf[(size_t)(n + 3) * 64 + lane] = (unsigned short)bf16rne(a3);
    }
    __syncthreads();
  }
  // lane == channel: no cross-lane reduce needed
  atomicAdd(&ws[OFF_SUM + lane], bnsum);
  atomicAdd(&ws[OFF_SQ + lane], bnsq);
}

// ---------------------------------------------------------------------------
// K2: logits = feat@seg_w + seg_b; softmax->probs; argmax->segp; NLL partials.
// 1 wave per block; lanes packed as 3 points x 20 channels (60/64 useful).
// ---------------------------------------------------------------------------
__global__ __launch_bounds__(64) void seg_kernel(
    const float* __restrict__ feat, const float* __restrict__ seg_w,
    const float* __restrict__ seg_b, const int* __restrict__ segment,
    float* __restrict__ ws)
{
  __shared__ float fs[66][68];   // rows 64,65 zeroed pad (read by tail groups)
  __shared__ float lg[64][21];   // pad 21 -> conflict-free per-lane row reads
  float* acc   = ws + OFF_ACC;
  int*   segp  = (int*)(ws + OFF_SEGPRED);
  float* probs = ws + OFF_PROBS;

  const int lane = threadIdx.x;
  const int sub  = lane / 20;        // 0..2 active, 3 = spare lanes
  const int ch   = lane % 20;

  float wreg[64];                    // seg_w[k][ch], static-indexed only
  #pragma unroll
  for (int k = 0; k < 64; ++k) wreg[k] = seg_w[k * 20 + ch];
  const float sbv = seg_b[ch];

  // zero the two pad rows once
  for (int i = lane; i < 136; i += 64) (&fs[64][0])[i] = 0.f;

  float nll_acc = 0.f, vld_acc = 0.f;

  for (int tile = blockIdx.x; tile < NTILES; tile += gridDim.x) {
    const int n0 = tile * 64;
    #pragma unroll
    for (int j = 0; j < 16; ++j) {
      const int flat = j * 64 + lane;
      const int p = flat >> 4, u = flat & 15;
      const int gp = n0 + p;
      float4 v = make_float4(0.f, 0.f, 0.f, 0.f);
      if (gp < NPTS) v = ((const float4*)(feat + (size_t)gp * 64))[u];
      *(float4*)&fs[p][u * 4] = v;
    }
    __syncthreads();

    #pragma unroll 1
    for (int g = 0; g < 22; ++g) {
      const int p = g * 3 + sub;
      const int pr = p < 65 ? p : 65;   // clamp spare lanes into zeroed pad row
      float a = sbv;
      #pragma unroll
      for (int k = 0; k < 64; k += 4) {
        const float4 f = *(const float4*)&fs[pr][k];
        a = fmaf(f.x, wreg[k], a); a = fmaf(f.y, wreg[k + 1], a);
        a = fmaf(f.z, wreg[k + 2], a); a = fmaf(f.w, wreg[k + 3], a);
      }
      if (sub < 3 && p < 64) lg[p][ch] = a;
    }
    __syncthreads();

    const int n = n0 + lane;
    if (n < NPTS) {
      float l[20];
      #pragma unroll
      for (int j = 0; j < 20; ++j) l[j] = lg[lane][j];
      const int seg = segment[n];
      const bool svalid = (seg != -1);
      const int sidx = seg < 0 ? 0 : (seg > 19 ? 19 : seg);
      float m = l[0]; int bi = 0;
      #pragma unroll
      for (int j = 1; j < 20; ++j) { if (l[j] > m) { m = l[j]; bi = j; } }
      float lsv = l[0];
      #pragma unroll
      for (int j = 1; j < 20; ++j) lsv = (j == sidx) ? l[j] : lsv;
      float se = 0.f;
      #pragma unroll
      for (int j = 0; j < 20; ++j) { l[j] = __expf(l[j] - m); se += l[j]; }
      const float inv = 1.f / se;
      float4* pr4 = (float4*)(probs + (size_t)n * 20);
      pr4[0] = make_float4(l[0]*inv,  l[1]*inv,  l[2]*inv,  l[3]*inv);
      pr4[1] = make_float4(l[4]*inv,  l[5]*inv,  l[6]*inv,  l[7]*inv);
      pr4[2] = make_float4(l[8]*inv,  l[9]*inv,  l[10]*inv, l[11]*inv);
      pr4[3] = make_float4(l[12]*inv, l[13]*inv, l[14]*inv, l[15]*inv);
      pr4[4] = make_float4(l[16]*inv, l[17]*inv, l[18]*inv, l[19]*inv);
      segp[n] = bi;
      nll_acc += svalid ? (m + __logf(se) - lsv) : 0.f;
      vld_acc += svalid ? 1.f : 0.f;
    }
    __syncthreads();
  }

  #pragma unroll
  for (int o = 32; o > 0; o >>= 1) {
    nll_acc += __shfl_down(nll_acc, o);
    vld_acc += __shfl_down(vld_acc, o);
  }
  if (lane == 0) { atomicAdd(&acc[0], nll_acc); atomicAdd(&acc[1], vld_acc); }
}

// ---------------------------------------------------------------------------
// K3: BN (recomputed per block) + ReLU + w2 head + L1/cosine partials
// ---------------------------------------------------------------------------
__global__ __launch_bounds__(256, 6) void bias_loss_kernel(
    const float* __restrict__ coord, const float* __restrict__ cent,
    const float* __restrict__ gamma, const float* __restrict__ beta,
    const float* __restrict__ w2, const float* __restrict__ b2,
    const int* __restrict__ instance, float* __restrict__ ws)
{
  __shared__ float scs[64], shs[64];
  __shared__ float r0[4], r1[4], r2[4];
  float* acc = ws + OFF_ACC;
  const unsigned short* hbuf = (const unsigned short*)(ws + OFF_H);

  const int tid = threadIdx.x;
  if (tid < 64) {
    const float mu  = ws[OFF_SUM + tid] * (1.f / NPTS);
    const float var = ws[OFF_SQ  + tid] * (1.f / NPTS) - mu * mu;
    const float sc = gamma[tid] * rsqrtf(var + 0.001f);
    scs[tid] = sc;
    shs[tid] = beta[tid] - mu * sc;   // b1 cancels through BN
  }
  __syncthreads();

  const int n = blockIdx.x * 256 + tid;
  float l1v = 0.f, cosv = 0.f, mk = 0.f;
  if (n < NPTS) {
    uint4 hv[8];
    const uint4* hp = (const uint4*)(hbuf + (size_t)n * 64);
    #pragma unroll
    for (int i = 0; i < 8; ++i) hv[i] = hp[i];

    float bx = b2[0], by = b2[1], bz = b2[2];
    #pragma unroll
    for (int i = 0; i < 8; ++i) {
      const unsigned uu[4] = {hv[i].x, hv[i].y, hv[i].z, hv[i].w};
      #pragma unroll
      for (int j = 0; j < 4; ++j) {
        const int c = i * 8 + j * 2;
        const float lo = __uint_as_float(uu[j] << 16);
        const float hi = __uint_as_float(uu[j] & 0xffff0000u);
        const float h0 = fmaxf(fmaf(lo, scs[c],     shs[c]),     0.f);
        const float h1 = fmaxf(fmaf(hi, scs[c + 1], shs[c + 1]), 0.f);
        bx = fmaf(h0, w2[c * 3 + 0], bx);
        by = fmaf(h0, w2[c * 3 + 1], by);
        bz = fmaf(h0, w2[c * 3 + 2], bz);
        bx = fmaf(h1, w2[c * 3 + 3], bx);
        by = fmaf(h1, w2[c * 3 + 4], by);
        bz = fmaf(h1, w2[c * 3 + 5], bz);
      }
    }
    const float cx = coord[(size_t)n*3+0], cy = coord[(size_t)n*3+1], cz = coord[(size_t)n*3+2];
    const float ex = cent[(size_t)n*3+0],  ey = cent[(size_t)n*3+1],  ez = cent[(size_t)n*3+2];
    const float gx = ex - cx, gy = ey - cy, gz = ez - cz;
    const float dx = bx - gx, dy = by - gy, dz = bz - gz;
    const float l1 = fabsf(dx) + fabsf(dy) + fabsf(dz);
    const float npn = sqrtf(bx*bx + by*by + bz*bz) + 1e-8f;
    const float ngn = sqrtf(gx*gx + gy*gy + gz*gz) + 1e-8f;
    const float cv = -(bx*gx + by*gy + bz*gz) / (npn * ngn);
    mk = (instance[n] != -1) ? 1.f : 0.f;
    l1v = l1 * mk;
    cosv = cv * mk;
  }
  #pragma unroll
  for (int o = 32; o > 0; o >>= 1) {
    l1v  += __shfl_down(l1v, o);
    cosv += __shfl_down(cosv, o);
    mk   += __shfl_down(mk, o);
  }
  if ((tid & 63) == 0) { r0[tid>>6] = l1v; r1[tid>>6] = cosv; r2[tid>>6] = mk; }
  __syncthreads();
  if (tid == 0) {
    atomicAdd(&acc[2], r0[0]+r0[1]+r0[2]+r0[3]);
    atomicAdd(&acc[3], r1[0]+r1[1]+r1[2]+r1[3]);
    atomicAdd(&acc[4], r2[0]+r2[1]+r2[2]+r2[3]);
  }
}

__global__ __launch_bounds__(256) void assign_kernel(
    const int* __restrict__ prop_ids, const int* __restrict__ point_ids, float* __restrict__ ws)
{
  unsigned* bitmap = (unsigned*)(ws + OFF_BITMAP);
  const int i = blockIdx.x * 256 + threadIdx.x;
  if (i < M_ASSIGN) {
    const int p = prop_ids[i];
    const int n = point_ids[i];
    atomicOr(&bitmap[p * WPR + (n >> 5)], 1u << (n & 31));
  }
}

// ---------------------------------------------------------------------------
// Per-proposal score (inline first-index search + final loss on p==0)
// ---------------------------------------------------------------------------
__global__ __launch_bounds__(256) void score_kernel(
    const int* __restrict__ prop_ids, const int* __restrict__ point_ids,
    const float* __restrict__ ws, float* __restrict__ out)
{
  const unsigned* bitmap = (const unsigned*)(ws + OFF_BITMAP);
  const float* probs = ws + OFF_PROBS;
  const int* segp = (const int*)(ws + OFF_SEGPRED);
  __shared__ float rs[4];
  __shared__ int rc[4];
  const int p = blockIdx.x;
  const int tid = threadIdx.x;

  int lo = 0, hi = M_ASSIGN;
  while (lo < hi) { const int mid = (lo + hi) >> 1; if (prop_ids[mid] < p) lo = mid + 1; else hi = mid; }
  if (lo > M_ASSIGN - 1) lo = M_ASSIGN - 1;
  const int cp = segp[point_ids[lo]];

  float s = 0.f; int cnt = 0;
  for (int w = tid; w < WPR; w += 256) {
    unsigned bits = bitmap[p * WPR + w];
    cnt += __popc(bits);
    while (bits) {
      const int b = __ffs(bits) - 1;
      bits &= bits - 1;
      const int n = (w << 5) + b;
      s += probs[(size_t)n * 20 + cp];
    }
  }
  #pragma unroll
  for (int o = 32; o > 0; o >>= 1) { s += __shfl_down(s, o); cnt += __shfl_down(cnt, o); }
  if ((tid & 63) == 0) { rs[tid>>6] = s; rc[tid>>6] = cnt; }
  __syncthreads();
  if (tid == 0) {
    const float st = rs[0]+rs[1]+rs[2]+rs[3];
    const int ct = rc[0]+rc[1]+rc[2]+rc[3];
    const bool mk = ct > 100;
    out[1 + p]   = mk ? st / (float)(ct > 1 ? ct : 1) : 0.f;
    out[129 + p] = mk ? 1.f : 0.f;
    if (p == 0) {
      const float segl = ws[0] / fmaxf(ws[1], 1.f);
      const float d = ws[4] + 1e-8f;
      out[0] = segl + ws[2] / d + ws[3] / d;
    }
  }
}

extern "C" void kernel_launch(void* const* d_in, const int* in_sizes, int n_in,
                              void* d_out, int out_size, void* d_ws, size_t ws_size,
                              hipStream_t stream) {
  const float* feat    = (const float*)d_in[0];
  const float* coord   = (const float*)d_in[1];
  const float* cent    = (const float*)d_in[2];
  const float* w1      = (const float*)d_in[3];
  // d_in[4] = b1 : cancels through BN, unused
  const float* gamma   = (const float*)d_in[5];
  const float* beta    = (const float*)d_in[6];
  const float* w2      = (const float*)d_in[7];
  const float* b2      = (const float*)d_in[8];
  const float* seg_w   = (const float*)d_in[9];
  const float* seg_b   = (const float*)d_in[10];
  const int* segment   = (const int*)d_in[11];
  const int* instance  = (const int*)d_in[12];
  const int* prop_ids  = (const int*)d_in[13];
  const int* point_ids = (const int*)d_in[14];
  float* out = (float*)d_out;
  float* ws  = (float*)d_ws;

  // zero accumulators + BN sums + bitmap
  hipMemsetAsync(d_ws, 0, (size_t)(OFF_BITMAP + 2000000) * sizeof(float), stream);

  h_kernel<<<2048, 64, 0, stream>>>(feat, w1, ws);
  seg_kernel<<<2048, 64, 0, stream>>>(feat, seg_w, seg_b, segment, ws);
  bias_loss_kernel<<<1954, 256, 0, stream>>>(coord, cent, gamma, beta, w2, b2, instance, ws);
  assign_kernel<<<1563, 256, 0, stream>>>(prop_ids, point_ids, ws);
  score_kernel<<<128, 256, 0, stream>>>(prop_ids, point_ids, ws, out);
}

// Round 7
// 302.077 us; speedup vs baseline: 2.3877x; 1.6028x over previous
//
#include <hip/hip_runtime.h>
#include <math.h>

#define NPTS 500000
#define M_ASSIGN 400000
#define WPR 15625   // 500000/32 words per bitmap row
#define NTILES 7813 // ceil(500000/64)

// workspace layout (float units)
constexpr int    OFF_ACC      = 0;        // [0]=nll_sum [1]=valid_cnt [2]=l1_sum [3]=cos_sum [4]=mask_sum
constexpr int    OFF_SUM      = 64;       // 64 BN sums (of raw h, no b1)
constexpr int    OFF_SQ       = 128;      // 64 BN sumsq
constexpr int    OFF_BITMAP   = 320;      // 2,000,000 uint32
constexpr int    OFF_SEGPRED  = 2000320;  // 500,000 int
constexpr int    OFF_PROBS    = 2500448;  // 10,000,000 float
constexpr size_t OFF_H        = 12500448; // 16,000,000 bf16

typedef __attribute__((ext_vector_type(8))) short short8v;
typedef __attribute__((ext_vector_type(4))) float f32x4;

__device__ inline unsigned bf16rne(float x) {
  unsigned u = __float_as_uint(x);
  return (u + 0x7fffu + ((u >> 16) & 1u)) >> 16;
}

// ---------------------------------------------------------------------------
// K1 (MFMA): [h | seg logits] = feat @ [w1 | seg_w]  (bf16 in, f32 acc)
// Block = 256 thr (4 waves); per tile of 64 points each wave owns 16 points
// and all 96 (padded) channels: 6 n-tiles x 2 K-steps = 12 MFMA / wave.
// B-frags live in VGPRs (built once). A read direct from global (coalesced).
// Fused: h->bf16 store, BN stats, softmax->probs, argmax->segp, NLL.
// ---------------------------------------------------------------------------
__global__ __launch_bounds__(256, 3) void gemm_kernel(
    const float* __restrict__ feat, const float* __restrict__ w1,
    const float* __restrict__ seg_w, const float* __restrict__ seg_b,
    const int* __restrict__ segment, float* __restrict__ ws)
{
  __shared__ float lg[4][16][22];   // per-wave logit transpose buffer

  float* acc   = ws + OFF_ACC;
  int*   segp  = (int*)(ws + OFF_SEGPRED);
  float* probs = ws + OFF_PROBS;
  unsigned short* hbuf = (unsigned short*)(ws + OFF_H);

  const int tid  = threadIdx.x;
  const int lane = tid & 63;
  const int w    = tid >> 6;   // wave id 0..3
  const int col  = lane & 15;  // N-within-tile (channel) / A-row (point)
  const int kg   = lane >> 4;  // 0..3 k-group

  // ---- build B fragments (once) ----
  auto mkb = [&](int t, int ks) -> short8v {
    union { short8v v; unsigned short u[8]; } bu;
    #pragma unroll
    for (int i = 0; i < 8; ++i) {
      const int k = ks * 32 + kg * 8 + i;
      float v;
      if (t < 4)       v = w1[k * 64 + t * 16 + col];
      else if (t == 4) v = seg_w[k * 20 + col];
      else             v = (col < 4) ? seg_w[k * 20 + 16 + col] : 0.f;
      bu.u[i] = (unsigned short)bf16rne(v);
    }
    return bu.v;
  };
  const short8v B00 = mkb(0,0), B01 = mkb(0,1);
  const short8v B10 = mkb(1,0), B11 = mkb(1,1);
  const short8v B20 = mkb(2,0), B21 = mkb(2,1);
  const short8v B30 = mkb(3,0), B31 = mkb(3,1);
  const short8v B40 = mkb(4,0), B41 = mkb(4,1);
  const short8v B50 = mkb(5,0), B51 = mkb(5,1);

  const float sb4 = seg_b[col];
  const float sb5 = (col < 4) ? seg_b[16 + col] : 0.f;

  float bnsum[4] = {0.f, 0.f, 0.f, 0.f};
  float bnsq[4]  = {0.f, 0.f, 0.f, 0.f};
  float nll_acc = 0.f, vld_acc = 0.f;

  for (int tile = blockIdx.x; tile < NTILES; tile += gridDim.x) {
    const int n0 = tile * 64;
    const int prow = n0 + w * 16 + col;   // this lane's A row (point)

    // ---- A fragments: direct global read + bf16 convert ----
    f32x4 a0 = {0.f,0.f,0.f,0.f}, a1 = a0, a2 = a0, a3 = a0;
    if (prow < NPTS) {
      const float* fp = feat + (size_t)prow * 64 + kg * 8;
      a0 = *(const f32x4*)(fp);        // kstep0: k = kg*8 .. +3
      a1 = *(const f32x4*)(fp + 4);    //         k = kg*8+4 .. +7
      a2 = *(const f32x4*)(fp + 32);   // kstep1
      a3 = *(const f32x4*)(fp + 36);
    }
    union { short8v v; unsigned short u[8]; } A0, A1;
    #pragma unroll
    for (int i = 0; i < 4; ++i) {
      A0.u[i]     = (unsigned short)bf16rne(a0[i]);
      A0.u[4 + i] = (unsigned short)bf16rne(a1[i]);
      A1.u[i]     = (unsigned short)bf16rne(a2[i]);
      A1.u[4 + i] = (unsigned short)bf16rne(a3[i]);
    }

    // ---- 12 MFMA ----
    f32x4 ac0 = {0.f,0.f,0.f,0.f}, ac1 = ac0, ac2 = ac0, ac3 = ac0;
    f32x4 ac4 = {sb4, sb4, sb4, sb4};
    f32x4 ac5 = {sb5, sb5, sb5, sb5};
    ac0 = __builtin_amdgcn_mfma_f32_16x16x32_bf16(A0.v, B00, ac0, 0, 0, 0);
    ac0 = __builtin_amdgcn_mfma_f32_16x16x32_bf16(A1.v, B01, ac0, 0, 0, 0);
    ac1 = __builtin_amdgcn_mfma_f32_16x16x32_bf16(A0.v, B10, ac1, 0, 0, 0);
    ac1 = __builtin_amdgcn_mfma_f32_16x16x32_bf16(A1.v, B11, ac1, 0, 0, 0);
    ac2 = __builtin_amdgcn_mfma_f32_16x16x32_bf16(A0.v, B20, ac2, 0, 0, 0);
    ac2 = __builtin_amdgcn_mfma_f32_16x16x32_bf16(A1.v, B21, ac2, 0, 0, 0);
    ac3 = __builtin_amdgcn_mfma_f32_16x16x32_bf16(A0.v, B30, ac3, 0, 0, 0);
    ac3 = __builtin_amdgcn_mfma_f32_16x16x32_bf16(A1.v, B31, ac3, 0, 0, 0);
    ac4 = __builtin_amdgcn_mfma_f32_16x16x32_bf16(A0.v, B40, ac4, 0, 0, 0);
    ac4 = __builtin_amdgcn_mfma_f32_16x16x32_bf16(A1.v, B41, ac4, 0, 0, 0);
    ac5 = __builtin_amdgcn_mfma_f32_16x16x32_bf16(A0.v, B50, ac5, 0, 0, 0);
    ac5 = __builtin_amdgcn_mfma_f32_16x16x32_bf16(A1.v, B51, ac5, 0, 0, 0);

    // ---- epilogue: h store (bf16) + BN partials ----
    // C layout (m89): col = lane&15 (channel), row = kg*4 + r (point)
    #pragma unroll
    for (int r = 0; r < 4; ++r) {
      const int p = n0 + w * 16 + kg * 4 + r;
      const float v0 = ac0[r], v1 = ac1[r], v2 = ac2[r], v3 = ac3[r];
      bnsum[0] += v0; bnsq[0] += v0 * v0;
      bnsum[1] += v1; bnsq[1] += v1 * v1;
      bnsum[2] += v2; bnsq[2] += v2 * v2;
      bnsum[3] += v3; bnsq[3] += v3 * v3;
      if (p < NPTS) {
        unsigned short* hp = hbuf + (size_t)p * 64 + col;
        hp[0]  = (unsigned short)bf16rne(v0);
        hp[16] = (unsigned short)bf16rne(v1);
        hp[32] = (unsigned short)bf16rne(v2);
        hp[48] = (unsigned short)bf16rne(v3);
      }
      // seg logits -> LDS (per-wave slice, within-wave consume)
      lg[w][kg * 4 + r][col] = ac4[r];
      if (col < 4) lg[w][kg * 4 + r][16 + col] = ac5[r];
    }
    __syncthreads();

    // ---- softmax / argmax / NLL: lane j<16 handles point n0+w*16+j ----
    const int n = n0 + w * 16 + lane;
    if (lane < 16 && n < NPTS) {
      float l[20];
      #pragma unroll
      for (int j = 0; j < 20; ++j) l[j] = lg[w][lane][j];
      const int seg = segment[n];
      const bool svalid = (seg != -1);
      const int sidx = seg < 0 ? 0 : (seg > 19 ? 19 : seg);
      float m = l[0]; int bi = 0;
      #pragma unroll
      for (int j = 1; j < 20; ++j) { if (l[j] > m) { m = l[j]; bi = j; } }
      float lsv = l[0];
      #pragma unroll
      for (int j = 1; j < 20; ++j) lsv = (j == sidx) ? l[j] : lsv;
      float se = 0.f;
      #pragma unroll
      for (int j = 0; j < 20; ++j) { l[j] = __expf(l[j] - m); se += l[j]; }
      const float inv = 1.f / se;
      float4* pr4 = (float4*)(probs + (size_t)n * 20);
      pr4[0] = make_float4(l[0]*inv,  l[1]*inv,  l[2]*inv,  l[3]*inv);
      pr4[1] = make_float4(l[4]*inv,  l[5]*inv,  l[6]*inv,  l[7]*inv);
      pr4[2] = make_float4(l[8]*inv,  l[9]*inv,  l[10]*inv, l[11]*inv);
      pr4[3] = make_float4(l[12]*inv, l[13]*inv, l[14]*inv, l[15]*inv);
      pr4[4] = make_float4(l[16]*inv, l[17]*inv, l[18]*inv, l[19]*inv);
      segp[n] = bi;
      nll_acc += svalid ? (m + __logf(se) - lsv) : 0.f;
      vld_acc += svalid ? 1.f : 0.f;
    }
    __syncthreads();
  }

  // ---- BN reduce: lanes {j, j+16, j+32, j+48} hold same channel t*16+j ----
  #pragma unroll
  for (int t = 0; t < 4; ++t) {
    float s = bnsum[t], q = bnsq[t];
    s += __shfl_down(s, 32); s += __shfl_down(s, 16);
    q += __shfl_down(q, 32); q += __shfl_down(q, 16);
    if (lane < 16) {
      atomicAdd(&ws[OFF_SUM + t * 16 + lane], s);
      atomicAdd(&ws[OFF_SQ  + t * 16 + lane], q);
    }
  }
  float s = nll_acc, v = vld_acc;
  #pragma unroll
  for (int o = 32; o > 0; o >>= 1) { s += __shfl_down(s, o); v += __shfl_down(v, o); }
  if (lane == 0) { atomicAdd(&acc[0], s); atomicAdd(&acc[1], v); }
}

// ---------------------------------------------------------------------------
// K2: BN (recomputed per block) + ReLU + w2 head + L1/cosine partials
// ---------------------------------------------------------------------------
__global__ __launch_bounds__(256, 6) void bias_loss_kernel(
    const float* __restrict__ coord, const float* __restrict__ cent,
    const float* __restrict__ gamma, const float* __restrict__ beta,
    const float* __restrict__ w2, const float* __restrict__ b2,
    const int* __restrict__ instance, float* __restrict__ ws)
{
  __shared__ float scs[64], shs[64];
  __shared__ float r0[4], r1[4], r2[4];
  float* acc = ws + OFF_ACC;
  const unsigned short* hbuf = (const unsigned short*)(ws + OFF_H);

  const int tid = threadIdx.x;
  if (tid < 64) {
    const float mu  = ws[OFF_SUM + tid] * (1.f / NPTS);
    const float var = ws[OFF_SQ  + tid] * (1.f / NPTS) - mu * mu;
    const float sc = gamma[tid] * rsqrtf(var + 0.001f);
    scs[tid] = sc;
    shs[tid] = beta[tid] - mu * sc;   // b1 cancels through BN
  }
  __syncthreads();

  const int n = blockIdx.x * 256 + tid;
  float l1v = 0.f, cosv = 0.f, mk = 0.f;
  if (n < NPTS) {
    uint4 hv[8];
    const uint4* hp = (const uint4*)(hbuf + (size_t)n * 64);
    #pragma unroll
    for (int i = 0; i < 8; ++i) hv[i] = hp[i];

    float bx = b2[0], by = b2[1], bz = b2[2];
    #pragma unroll
    for (int i = 0; i < 8; ++i) {
      const unsigned uu[4] = {hv[i].x, hv[i].y, hv[i].z, hv[i].w};
      #pragma unroll
      for (int j = 0; j < 4; ++j) {
        const int c = i * 8 + j * 2;
        const float lo = __uint_as_float(uu[j] << 16);
        const float hi = __uint_as_float(uu[j] & 0xffff0000u);
        const float h0 = fmaxf(fmaf(lo, scs[c],     shs[c]),     0.f);
        const float h1 = fmaxf(fmaf(hi, scs[c + 1], shs[c + 1]), 0.f);
        bx = fmaf(h0, w2[c * 3 + 0], bx);
        by = fmaf(h0, w2[c * 3 + 1], by);
        bz = fmaf(h0, w2[c * 3 + 2], bz);
        bx = fmaf(h1, w2[c * 3 + 3], bx);
        by = fmaf(h1, w2[c * 3 + 4], by);
        bz = fmaf(h1, w2[c * 3 + 5], bz);
      }
    }
    const float cx = coord[(size_t)n*3+0], cy = coord[(size_t)n*3+1], cz = coord[(size_t)n*3+2];
    const float ex = cent[(size_t)n*3+0],  ey = cent[(size_t)n*3+1],  ez = cent[(size_t)n*3+2];
    const float gx = ex - cx, gy = ey - cy, gz = ez - cz;
    const float dx = bx - gx, dy = by - gy, dz = bz - gz;
    const float l1 = fabsf(dx) + fabsf(dy) + fabsf(dz);
    const float npn = sqrtf(bx*bx + by*by + bz*bz) + 1e-8f;
    const float ngn = sqrtf(gx*gx + gy*gy + gz*gz) + 1e-8f;
    const float cv = -(bx*gx + by*gy + bz*gz) / (npn * ngn);
    mk = (instance[n] != -1) ? 1.f : 0.f;
    l1v = l1 * mk;
    cosv = cv * mk;
  }
  #pragma unroll
  for (int o = 32; o > 0; o >>= 1) {
    l1v  += __shfl_down(l1v, o);
    cosv += __shfl_down(cosv, o);
    mk   += __shfl_down(mk, o);
  }
  if ((tid & 63) == 0) { r0[tid>>6] = l1v; r1[tid>>6] = cosv; r2[tid>>6] = mk; }
  __syncthreads();
  if (tid == 0) {
    atomicAdd(&acc[2], r0[0]+r0[1]+r0[2]+r0[3]);
    atomicAdd(&acc[3], r1[0]+r1[1]+r1[2]+r1[3]);
    atomicAdd(&acc[4], r2[0]+r2[1]+r2[2]+r2[3]);
  }
}

__global__ __launch_bounds__(256) void assign_kernel(
    const int* __restrict__ prop_ids, const int* __restrict__ point_ids, float* __restrict__ ws)
{
  unsigned* bitmap = (unsigned*)(ws + OFF_BITMAP);
  const int i = blockIdx.x * 256 + threadIdx.x;
  if (i < M_ASSIGN) {
    const int p = prop_ids[i];
    const int n = point_ids[i];
    atomicOr(&bitmap[p * WPR + (n >> 5)], 1u << (n & 31));
  }
}

// ---------------------------------------------------------------------------
// Per-proposal score (inline first-index search + final loss on p==0)
// ---------------------------------------------------------------------------
__global__ __launch_bounds__(256) void score_kernel(
    const int* __restrict__ prop_ids, const int* __restrict__ point_ids,
    const float* __restrict__ ws, float* __restrict__ out)
{
  const unsigned* bitmap = (const unsigned*)(ws + OFF_BITMAP);
  const float* probs = ws + OFF_PROBS;
  const int* segp = (const int*)(ws + OFF_SEGPRED);
  __shared__ float rs[4];
  __shared__ int rc[4];
  const int p = blockIdx.x;
  const int tid = threadIdx.x;

  int lo = 0, hi = M_ASSIGN;
  while (lo < hi) { const int mid = (lo + hi) >> 1; if (prop_ids[mid] < p) lo = mid + 1; else hi = mid; }
  if (lo > M_ASSIGN - 1) lo = M_ASSIGN - 1;
  const int cp = segp[point_ids[lo]];

  float s = 0.f; int cnt = 0;
  for (int w = tid; w < WPR; w += 256) {
    unsigned bits = bitmap[p * WPR + w];
    cnt += __popc(bits);
    while (bits) {
      const int b = __ffs(bits) - 1;
      bits &= bits - 1;
      const int n = (w << 5) + b;
      s += probs[(size_t)n * 20 + cp];
    }
  }
  #pragma unroll
  for (int o = 32; o > 0; o >>= 1) { s += __shfl_down(s, o); cnt += __shfl_down(cnt, o); }
  if ((tid & 63) == 0) { rs[tid>>6] = s; rc[tid>>6] = cnt; }
  __syncthreads();
  if (tid == 0) {
    const float st = rs[0]+rs[1]+rs[2]+rs[3];
    const int ct = rc[0]+rc[1]+rc[2]+rc[3];
    const bool mk = ct > 100;
    out[1 + p]   = mk ? st / (float)(ct > 1 ? ct : 1) : 0.f;
    out[129 + p] = mk ? 1.f : 0.f;
    if (p == 0) {
      const float segl = ws[0] / fmaxf(ws[1], 1.f);
      const float d = ws[4] + 1e-8f;
      out[0] = segl + ws[2] / d + ws[3] / d;
    }
  }
}

extern "C" void kernel_launch(void* const* d_in, const int* in_sizes, int n_in,
                              void* d_out, int out_size, void* d_ws, size_t ws_size,
                              hipStream_t stream) {
  const float* feat    = (const float*)d_in[0];
  const float* coord   = (const float*)d_in[1];
  const float* cent    = (const float*)d_in[2];
  const float* w1      = (const float*)d_in[3];
  // d_in[4] = b1 : cancels through BN, unused
  const float* gamma   = (const float*)d_in[5];
  const float* beta    = (const float*)d_in[6];
  const float* w2      = (const float*)d_in[7];
  const float* b2      = (const float*)d_in[8];
  const float* seg_w   = (const float*)d_in[9];
  const float* seg_b   = (const float*)d_in[10];
  const int* segment   = (const int*)d_in[11];
  const int* instance  = (const int*)d_in[12];
  const int* prop_ids  = (const int*)d_in[13];
  const int* point_ids = (const int*)d_in[14];
  float* out = (float*)d_out;
  float* ws  = (float*)d_ws;

  // zero accumulators + BN sums + bitmap
  hipMemsetAsync(d_ws, 0, (size_t)(OFF_BITMAP + 2000000) * sizeof(float), stream);

  gemm_kernel<<<1024, 256, 0, stream>>>(feat, w1, seg_w, seg_b, segment, ws);
  bias_loss_kernel<<<1954, 256, 0, stream>>>(coord, cent, gamma, beta, w2, b2, instance, ws);
  assign_kernel<<<1563, 256, 0, stream>>>(prop_ids, point_ids, ws);
  score_kernel<<<128, 256, 0, stream>>>(prop_ids, point_ids, ws, out);
}